// Round 4
// baseline (193.320 us; speedup 1.0000x reference)
//
#include <hip/hip_runtime.h>

#define N_NODES 100000
#define N_EDGES 1600000
#define NUM_HEADS 4
#define NEG_SLOPE 0.2f
#define LDSTRIDE 136   // 16-bit elems: 272 B rows (68 dwords ≡ 4 mod 32 banks)
#define SEG_BLOCKS 1563   // ceil(400000/256) threads, 4 edges each

typedef __attribute__((ext_vector_type(8))) short bf16x8;
typedef __attribute__((ext_vector_type(4))) float f32x4;

__device__ __forceinline__ unsigned short f2bf(float x) {
    union { float f; unsigned u; } v; v.f = x;
    unsigned r = v.u + 0x7fffu + ((v.u >> 16) & 1u);   // RN-even
    return (unsigned short)(r >> 16);
}
__device__ __forceinline__ unsigned short f2h(float x) {
    union { _Float16 h; unsigned short u; } v; v.h = (_Float16)x;  // v_cvt_f16_f32 RNE
    return v.u;
}

// ---------------------------------------------------------------------------
// Kernel 0: fused seg + prep (unchanged from round 3 — attribution control).
// ---------------------------------------------------------------------------
__global__ __launch_bounds__(256) void prep_seg_kernel(
    const int* __restrict__ dst, int* __restrict__ seg,
    const float* __restrict__ W, const float* __restrict__ attn_l,
    const float* __restrict__ attn_r, unsigned short* __restrict__ Wt2)
{
    const int b = blockIdx.x;
    if (b < SEG_BLOCKS) {
        int i4 = b * 256 + threadIdx.x;
        if (i4 >= N_EDGES / 4) return;
        const int e0 = 4 * i4;
        const int4 d = ((const int4*)dst)[i4];
        const int dp = (e0 == 0) ? -1 : dst[e0 - 1];
        for (int n = dp + 1; n <= d.x; ++n) seg[n] = e0;
        for (int n = d.x + 1; n <= d.y; ++n) seg[n] = e0 + 1;
        for (int n = d.y + 1; n <= d.z; ++n) seg[n] = e0 + 2;
        for (int n = d.z + 1; n <= d.w; ++n) seg[n] = e0 + 3;
        if (e0 + 4 == N_EDGES)
            for (int n = d.w + 1; n <= N_NODES; ++n) seg[n] = N_EDGES;
    } else {
        int idx = (b - SEG_BLOCKS) * 256 + threadIdx.x;   // [0, 17408)
        if (idx >= 136 * 128) return;
        int n = idx >> 7, k = idx & 127;
        if (n < 128) {
            Wt2[idx] = f2bf(W[k * 128 + n]);
        } else {
            int h = (n - 128) & 3;
            const float* av = ((n - 128) < 4 ? attn_l : attn_r) + h * 32;
            const float* col = W + k * 128 + h * 32;
            float s = 0.f;
#pragma unroll
            for (int d2 = 0; d2 < 32; ++d2) s += col[d2] * av[d2];
            Wt2[idx] = f2bf(s);
        }
    }
}

// ---------------------------------------------------------------------------
// Kernel 1: [ft | el | er] = bf16(feat) @ Wt2^T via MFMA 16x16x32.
// Unchanged from round 3 (attribution control).
// ---------------------------------------------------------------------------
__global__ __launch_bounds__(256, 3) void gemm_kernel(
    const float* __restrict__ feat, const unsigned short* __restrict__ Wt2,
    unsigned short* __restrict__ ft, float* __restrict__ el,
    float* __restrict__ er)
{
    __shared__ __align__(16) unsigned short B_lds[136 * LDSTRIDE];  // 36992 B
    const int t = threadIdx.x;
    const int nbase = blockIdx.x * 64;

    {   // stage Wt2 (136 rows x 128 k bf16) -> B_lds, coalesced 16B
        const int4* Wt4 = (const int4*)Wt2;
#pragma unroll
        for (int i = 0; i < 9; ++i) {
            int idx = t + 256 * i;            // [0,2304) guard to 2176
            if (idx < 2176) {
                int n = idx >> 4, cg = idx & 15;
                *(int4*)(&B_lds[n * LDSTRIDE + cg * 8]) = Wt4[idx];
            }
        }
    }
    __syncthreads();

    const int w = t >> 6, lane = t & 63;
    const int l15 = lane & 15, quad = lane >> 4;

    int g = nbase + w * 16 + l15;
    if (g >= N_NODES) g = N_NODES - 1;                  // clamped dup rows
    const float4* f4 = (const float4*)feat + (size_t)g * 32 + quad * 2;

    f32x4 acc[9];
#pragma unroll
    for (int c = 0; c < 9; ++c) acc[c] = (f32x4){0.f, 0.f, 0.f, 0.f};

    const unsigned short* Brow = &B_lds[l15 * LDSTRIDE + quad * 8];
    const unsigned short* Brow8 = &B_lds[(128 + (l15 & 7)) * LDSTRIDE + quad * 8];
#pragma unroll
    for (int ks = 0; ks < 4; ++ks) {
        float4 fa = f4[ks * 8];
        float4 fb = f4[ks * 8 + 1];
        bf16x8 a;
        a[0] = (short)f2bf(fa.x); a[1] = (short)f2bf(fa.y);
        a[2] = (short)f2bf(fa.z); a[3] = (short)f2bf(fa.w);
        a[4] = (short)f2bf(fb.x); a[5] = (short)f2bf(fb.y);
        a[6] = (short)f2bf(fb.z); a[7] = (short)f2bf(fb.w);
#pragma unroll
        for (int c = 0; c < 8; ++c) {
            bf16x8 b = *(const bf16x8*)(Brow + (c * 16) * LDSTRIDE + ks * 32);
            acc[c] = __builtin_amdgcn_mfma_f32_16x16x32_bf16(a, b, acc[c], 0, 0, 0);
        }
        bf16x8 b8 = *(const bf16x8*)(Brow8 + ks * 32);
        acc[8] = __builtin_amdgcn_mfma_f32_16x16x32_bf16(a, b8, acc[8], 0, 0, 0);
    }

    // el/er straight from acc8: col l15<4 -> el head l15; l15 in [4,8) -> er
#pragma unroll
    for (int reg = 0; reg < 4; ++reg) {
        const int gg = nbase + w * 16 + quad * 4 + reg;
        if (gg < N_NODES) {
            if (l15 < 4)      el[gg * 4 + l15] = acc[8][reg];
            else if (l15 < 8) er[gg * 4 + (l15 - 4)] = acc[8][reg];
        }
    }

    __syncthreads();   // everyone done reading B_lds -> reuse as ft scratch
#pragma unroll
    for (int c = 0; c < 8; ++c) {
#pragma unroll
        for (int reg = 0; reg < 4; ++reg) {
            B_lds[(w * 16 + quad * 4 + reg) * LDSTRIDE + c * 16 + l15] =
                f2h(acc[c][reg]);                       // FP16 pack
        }
    }
    __syncthreads();

    // coalesced repack: 64 rows x 128 cols fp16 -> global int4
#pragma unroll
    for (int i = 0; i < 4; ++i) {
        int idx = t + 256 * i;                // [0,1024)
        int node = idx >> 4, cg = idx & 15;
        int gg = nbase + node;
        if (gg < N_NODES) {
            int4 val = *(const int4*)(&B_lds[node * LDSTRIDE + cg * 8]);
            *(int4*)(&ft[(size_t)gg * 128 + cg * 8]) = val;
        }
    }
}

// ---------------------------------------------------------------------------
// Kernel 2: aggregation — TWO NODES PER WAVE, straight-line interleaved.
// Rounds 0-3 proved the kernel is NOT VALU/shuffle-throughput bound (three
// different instruction counts all gave ~74 us; HBM 48%, VALU 51%, occ 70%,
// nothing saturated). Mean degree 16 => one loop iteration per wave =>
// latency of the src->gather chain dominates. Fix: each wave now runs two
// independent node chains (node0 = 2i, node1 = 2i+1) with both chains' loads
// issued back-to-back in straight-line code -> ~2x outstanding memory
// requests per wave. Finished/degree-0 windows clamp to a duplicate row
// (L1 hit, p=0). 100000/8 = 12500 blocks exactly, no tail.
// ---------------------------------------------------------------------------
__global__ __launch_bounds__(256) void aggregate_kernel(
    const unsigned short* __restrict__ ft, const float* __restrict__ el,
    const float* __restrict__ er, const int* __restrict__ src,
    const int* __restrict__ seg, float* __restrict__ out)
{
    const int w = threadIdx.x >> 6;
    const int node0 = blockIdx.x * 8 + w * 2;     // < 100000 always
    const int node1 = node0 + 1;                  // < 100000 always
    const int lane = threadIdx.x & 63;
    const int qt = lane >> 4;         // quarter: edges c+4qt .. +3
    const int l15 = lane & 15;        // feature group: feats 8*l15..+7
    const int hf = l15 >> 2;          // head of this lane's features/scores

    const int beg0 = __builtin_amdgcn_readfirstlane(seg[node0]);
    const int end0 = __builtin_amdgcn_readfirstlane(seg[node0 + 1]);
    const int beg1 = __builtin_amdgcn_readfirstlane(seg[node1]);
    const int end1 = __builtin_amdgcn_readfirstlane(seg[node1 + 1]);
    const int last0 = (end0 > beg0) ? end0 - 1 : 0;   // degree-0 safe clamp
    const int last1 = (end1 > beg1) ? end1 - 1 : 0;
    const float er0 = er[node0 * 4 + hf];
    const float er1 = er[node1 * 4 + hf];

    float d0 = 0.f, d1 = 0.f;
    float4 a0A = make_float4(0.f, 0.f, 0.f, 0.f);
    float4 a0B = make_float4(0.f, 0.f, 0.f, 0.f);
    float4 a1A = make_float4(0.f, 0.f, 0.f, 0.f);
    float4 a1B = make_float4(0.f, 0.f, 0.f, 0.f);

    int c0 = beg0 + 4 * qt;           // this quarter's window base, node0
    int c1 = beg1 + 4 * qt;
    for (int t0 = beg0, t1 = beg1; t0 < end0 || t1 < end1;
         t0 += 16, t1 += 16, c0 += 16, c1 += 16) {
        // --- both src quads (broadcast within quarter, 8 loads in flight) ---
        int s40[4], s41[4];
#pragma unroll
        for (int k = 0; k < 4; ++k) {
            int ci = c0 + k; s40[k] = src[ci < end0 ? ci : last0];
        }
#pragma unroll
        for (int k = 0; k < 4; ++k) {
            int ci = c1 + k; s41[k] = src[ci < end1 ? ci : last1];
        }
        // --- both el gathers ---
        float ev0[4], ev1[4];
#pragma unroll
        for (int k = 0; k < 4; ++k) ev0[k] = el[s40[k] * 4 + hf];
#pragma unroll
        for (int k = 0; k < 4; ++k) ev1[k] = el[s41[k] * 4 + hf];
        // --- both score blocks ---
        float p0[4], p1[4];
#pragma unroll
        for (int k = 0; k < 4; ++k) {
            float e = ev0[k] + er0;
            e = (e > 0.f) ? e : NEG_SLOPE * e;
            p0[k] = (c0 + k < end0) ? __expf(e) : 0.f;
            d0 += p0[k];
        }
#pragma unroll
        for (int k = 0; k < 4; ++k) {
            float e = ev1[k] + er1;
            e = (e > 0.f) ? e : NEG_SLOPE * e;
            p1[k] = (c1 + k < end1) ? __expf(e) : 0.f;
            d1 += p1[k];
        }
        // --- both ft row-gather sets (8 x 16B in flight) ---
        uint4 v0[4], v1[4];
#pragma unroll
        for (int k = 0; k < 4; ++k)
            v0[k] = *(const uint4*)(ft + (((size_t)(unsigned)s40[k]) << 7) + l15 * 8);
#pragma unroll
        for (int k = 0; k < 4; ++k)
            v1[k] = *(const uint4*)(ft + (((size_t)(unsigned)s41[k]) << 7) + l15 * 8);
        // --- both FMA blocks (v_fma_mix_f32: f16 operand inside f32 FMA) ---
#pragma unroll
        for (int k = 0; k < 4; ++k) {
            const float pj = p0[k];
            asm("v_fma_mix_f32 %0, %2, %3, %0 op_sel_hi:[1,0,0]\n\t"
                "v_fma_mix_f32 %1, %2, %3, %1 op_sel:[1,0,0] op_sel_hi:[1,0,0]"
                : "+v"(a0A.x), "+v"(a0A.y) : "v"(v0[k].x), "v"(pj));
            asm("v_fma_mix_f32 %0, %2, %3, %0 op_sel_hi:[1,0,0]\n\t"
                "v_fma_mix_f32 %1, %2, %3, %1 op_sel:[1,0,0] op_sel_hi:[1,0,0]"
                : "+v"(a0A.z), "+v"(a0A.w) : "v"(v0[k].y), "v"(pj));
            asm("v_fma_mix_f32 %0, %2, %3, %0 op_sel_hi:[1,0,0]\n\t"
                "v_fma_mix_f32 %1, %2, %3, %1 op_sel:[1,0,0] op_sel_hi:[1,0,0]"
                : "+v"(a0B.x), "+v"(a0B.y) : "v"(v0[k].z), "v"(pj));
            asm("v_fma_mix_f32 %0, %2, %3, %0 op_sel_hi:[1,0,0]\n\t"
                "v_fma_mix_f32 %1, %2, %3, %1 op_sel:[1,0,0] op_sel_hi:[1,0,0]"
                : "+v"(a0B.z), "+v"(a0B.w) : "v"(v0[k].w), "v"(pj));
        }
#pragma unroll
        for (int k = 0; k < 4; ++k) {
            const float pj = p1[k];
            asm("v_fma_mix_f32 %0, %2, %3, %0 op_sel_hi:[1,0,0]\n\t"
                "v_fma_mix_f32 %1, %2, %3, %1 op_sel:[1,0,0] op_sel_hi:[1,0,0]"
                : "+v"(a1A.x), "+v"(a1A.y) : "v"(v1[k].x), "v"(pj));
            asm("v_fma_mix_f32 %0, %2, %3, %0 op_sel_hi:[1,0,0]\n\t"
                "v_fma_mix_f32 %1, %2, %3, %1 op_sel:[1,0,0] op_sel_hi:[1,0,0]"
                : "+v"(a1A.z), "+v"(a1A.w) : "v"(v1[k].y), "v"(pj));
            asm("v_fma_mix_f32 %0, %2, %3, %0 op_sel_hi:[1,0,0]\n\t"
                "v_fma_mix_f32 %1, %2, %3, %1 op_sel:[1,0,0] op_sel_hi:[1,0,0]"
                : "+v"(a1B.x), "+v"(a1B.y) : "v"(v1[k].z), "v"(pj));
            asm("v_fma_mix_f32 %0, %2, %3, %0 op_sel_hi:[1,0,0]\n\t"
                "v_fma_mix_f32 %1, %2, %3, %1 op_sel:[1,0,0] op_sel_hi:[1,0,0]"
                : "+v"(a1B.z), "+v"(a1B.w) : "v"(v1[k].w), "v"(pj));
        }
    }

    // reduce across quarters (lanes ^16, ^32); both nodes, d rides along
    d0  += __shfl_xor(d0, 16);  d1  += __shfl_xor(d1, 16);
    a0A.x += __shfl_xor(a0A.x, 16); a0A.y += __shfl_xor(a0A.y, 16);
    a0A.z += __shfl_xor(a0A.z, 16); a0A.w += __shfl_xor(a0A.w, 16);
    a0B.x += __shfl_xor(a0B.x, 16); a0B.y += __shfl_xor(a0B.y, 16);
    a0B.z += __shfl_xor(a0B.z, 16); a0B.w += __shfl_xor(a0B.w, 16);
    a1A.x += __shfl_xor(a1A.x, 16); a1A.y += __shfl_xor(a1A.y, 16);
    a1A.z += __shfl_xor(a1A.z, 16); a1A.w += __shfl_xor(a1A.w, 16);
    a1B.x += __shfl_xor(a1B.x, 16); a1B.y += __shfl_xor(a1B.y, 16);
    a1B.z += __shfl_xor(a1B.z, 16); a1B.w += __shfl_xor(a1B.w, 16);
    d0  += __shfl_xor(d0, 32);  d1  += __shfl_xor(d1, 32);
    a0A.x += __shfl_xor(a0A.x, 32); a0A.y += __shfl_xor(a0A.y, 32);
    a0A.z += __shfl_xor(a0A.z, 32); a0A.w += __shfl_xor(a0A.w, 32);
    a0B.x += __shfl_xor(a0B.x, 32); a0B.y += __shfl_xor(a0B.y, 32);
    a0B.z += __shfl_xor(a0B.z, 32); a0B.w += __shfl_xor(a0B.w, 32);
    a1A.x += __shfl_xor(a1A.x, 32); a1A.y += __shfl_xor(a1A.y, 32);
    a1A.z += __shfl_xor(a1A.z, 32); a1A.w += __shfl_xor(a1A.w, 32);
    a1B.x += __shfl_xor(a1B.x, 32); a1B.y += __shfl_xor(a1B.y, 32);
    a1B.z += __shfl_xor(a1B.z, 32); a1B.w += __shfl_xor(a1B.w, 32);

    if (qt == 0) {
        const float inv = (d0 > 0.f) ? 1.f / d0 : 0.f;   // degree-0 -> zeros
        float4 o0 = make_float4(a0A.x * inv, a0A.y * inv, a0A.z * inv, a0A.w * inv);
        float4 o1 = make_float4(a0B.x * inv, a0B.y * inv, a0B.z * inv, a0B.w * inv);
        float* op = out + (size_t)node0 * 128 + l15 * 8;
        *(float4*)op = o0;
        *(float4*)(op + 4) = o1;
    } else if (qt == 1) {
        const float inv = (d1 > 0.f) ? 1.f / d1 : 0.f;
        float4 o0 = make_float4(a1A.x * inv, a1A.y * inv, a1A.z * inv, a1A.w * inv);
        float4 o1 = make_float4(a1B.x * inv, a1B.y * inv, a1B.z * inv, a1B.w * inv);
        float* op = out + (size_t)node1 * 128 + l15 * 8;
        *(float4*)op = o0;
        *(float4*)(op + 4) = o1;
    }
}

// ---------------------------------------------------------------------------
extern "C" void kernel_launch(void* const* d_in, const int* in_sizes, int n_in,
                              void* d_out, int out_size, void* d_ws, size_t ws_size,
                              hipStream_t stream) {
    const float* feat   = (const float*)d_in[0];
    const int*   src    = (const int*)d_in[1];
    const int*   dst    = (const int*)d_in[2];
    const float* W      = (const float*)d_in[3];
    const float* attn_l = (const float*)d_in[4];
    const float* attn_r = (const float*)d_in[5];
    float* out = (float*)d_out;

    unsigned short* ft = (unsigned short*)d_ws;               // 12.8M fp16
    float* el  = (float*)(ft + (size_t)12800000);
    float* er  = el + 400000;
    unsigned short* Wt2 = (unsigned short*)(er + 400000);     // 136*128 bf16
    int* seg = (int*)(Wt2 + 136 * 128);                       // 100001 int

    prep_seg_kernel<<<SEG_BLOCKS + 68, 256, 0, stream>>>(
        dst, seg, W, attn_l, attn_r, Wt2);
    gemm_kernel<<<(N_NODES + 63) / 64, 256, 0, stream>>>(feat, Wt2, ft, el, er);
    aggregate_kernel<<<N_NODES / 8, 256, 0, stream>>>(
        ft, el, er, src, seg, out);
}

// Round 6
// 192.448 us; speedup vs baseline: 1.0045x; 1.0045x over previous
//
#include <hip/hip_runtime.h>

#define N_NODES 100000
#define N_EDGES 1600000
#define NUM_HEADS 4
#define NEG_SLOPE 0.2f
#define LDSTRIDE 136   // 16-bit elems: 272 B rows (68 dwords ≡ 4 mod 32 banks)
#define SEG_BLOCKS 1563   // ceil(400000/256) threads, 4 edges each

typedef __attribute__((ext_vector_type(8))) short bf16x8;
typedef __attribute__((ext_vector_type(4))) float f32x4;

__device__ __forceinline__ unsigned short f2bf(float x) {
    union { float f; unsigned u; } v; v.f = x;
    unsigned r = v.u + 0x7fffu + ((v.u >> 16) & 1u);   // RN-even
    return (unsigned short)(r >> 16);
}
__device__ __forceinline__ unsigned short f2h(float x) {
    union { _Float16 h; unsigned short u; } v; v.h = (_Float16)x;  // v_cvt_f16_f32 RNE
    return v.u;
}

// ---------------------------------------------------------------------------
// Kernel 0: fused seg + prep (unchanged).
// ---------------------------------------------------------------------------
__global__ __launch_bounds__(256) void prep_seg_kernel(
    const int* __restrict__ dst, int* __restrict__ seg,
    const float* __restrict__ W, const float* __restrict__ attn_l,
    const float* __restrict__ attn_r, unsigned short* __restrict__ Wt2)
{
    const int b = blockIdx.x;
    if (b < SEG_BLOCKS) {
        int i4 = b * 256 + threadIdx.x;
        if (i4 >= N_EDGES / 4) return;
        const int e0 = 4 * i4;
        const int4 d = ((const int4*)dst)[i4];
        const int dp = (e0 == 0) ? -1 : dst[e0 - 1];
        for (int n = dp + 1; n <= d.x; ++n) seg[n] = e0;
        for (int n = d.x + 1; n <= d.y; ++n) seg[n] = e0 + 1;
        for (int n = d.y + 1; n <= d.z; ++n) seg[n] = e0 + 2;
        for (int n = d.z + 1; n <= d.w; ++n) seg[n] = e0 + 3;
        if (e0 + 4 == N_EDGES)
            for (int n = d.w + 1; n <= N_NODES; ++n) seg[n] = N_EDGES;
    } else {
        int idx = (b - SEG_BLOCKS) * 256 + threadIdx.x;   // [0, 17408)
        if (idx >= 136 * 128) return;
        int n = idx >> 7, k = idx & 127;
        if (n < 128) {
            Wt2[idx] = f2bf(W[k * 128 + n]);
        } else {
            int h = (n - 128) & 3;
            const float* av = ((n - 128) < 4 ? attn_l : attn_r) + h * 32;
            const float* col = W + k * 128 + h * 32;
            float s = 0.f;
#pragma unroll
            for (int d2 = 0; d2 < 32; ++d2) s += col[d2] * av[d2];
            Wt2[idx] = f2bf(s);
        }
    }
}

// ---------------------------------------------------------------------------
// Kernel 1 v3: [ft | el | er] = bf16(feat) @ Wt2^T via MFMA 16x16x32.
// 128 nodes/block (782 blocks, half the Wt2 re-staging of the 64-node tile).
// 4 waves; wave w owns rows w*32..w*32+31 as TWO 16-row M-tiles sharing each
// B-fragment (ds_read once, 2 MFMAs -> 2:1 MFMA:ds_read, 72 MFMA/wave).
// feat float4 loads ISSUED BEFORE the Wt2->LDS staging phase so HBM latency
// hides under the LDS writes; fp32->bf16 conversion after the barrier.
// Epilogue identical layout per tile; ft repacked through B_lds (rows 0..127)
// for coalesced int4 stores.
// ---------------------------------------------------------------------------
__global__ __launch_bounds__(256, 3) void gemm_kernel(
    const float* __restrict__ feat, const unsigned short* __restrict__ Wt2,
    unsigned short* __restrict__ ft, float* __restrict__ el,
    float* __restrict__ er)
{
    __shared__ __align__(16) unsigned short B_lds[136 * LDSTRIDE];  // 36992 B
    const int t = threadIdx.x;
    const int nbase = blockIdx.x * 128;
    const int w = t >> 6, lane = t & 63;
    const int l15 = lane & 15, quad = lane >> 4;

    // --- issue feat loads FIRST (rows m0 = w*32+l15, m1 = m0+16) ---
    int g0 = nbase + w * 32 + l15;      if (g0 >= N_NODES) g0 = N_NODES - 1;
    int g1 = nbase + w * 32 + 16 + l15; if (g1 >= N_NODES) g1 = N_NODES - 1;
    const float4* f40 = (const float4*)feat + (size_t)g0 * 32 + quad * 2;
    const float4* f41 = (const float4*)feat + (size_t)g1 * 32 + quad * 2;
    float4 fr0[8], fr1[8];
#pragma unroll
    for (int ks = 0; ks < 4; ++ks) {
        fr0[2 * ks] = f40[ks * 8]; fr0[2 * ks + 1] = f40[ks * 8 + 1];
        fr1[2 * ks] = f41[ks * 8]; fr1[2 * ks + 1] = f41[ks * 8 + 1];
    }

    {   // stage Wt2 (136 rows x 128 k bf16) -> B_lds, coalesced 16B
        const int4* Wt4 = (const int4*)Wt2;
#pragma unroll
        for (int i = 0; i < 9; ++i) {
            int idx = t + 256 * i;            // [0,2304) guard to 2176
            if (idx < 2176) {
                int n = idx >> 4, cg = idx & 15;
                *(int4*)(&B_lds[n * LDSTRIDE + cg * 8]) = Wt4[idx];
            }
        }
    }
    __syncthreads();

    // --- convert prefetched fp32 -> bf16 A-fragments ---
    bf16x8 a0[4], a1[4];
#pragma unroll
    for (int ks = 0; ks < 4; ++ks) {
        float4 fa = fr0[2 * ks], fb = fr0[2 * ks + 1];
        a0[ks][0] = (short)f2bf(fa.x); a0[ks][1] = (short)f2bf(fa.y);
        a0[ks][2] = (short)f2bf(fa.z); a0[ks][3] = (short)f2bf(fa.w);
        a0[ks][4] = (short)f2bf(fb.x); a0[ks][5] = (short)f2bf(fb.y);
        a0[ks][6] = (short)f2bf(fb.z); a0[ks][7] = (short)f2bf(fb.w);
        fa = fr1[2 * ks]; fb = fr1[2 * ks + 1];
        a1[ks][0] = (short)f2bf(fa.x); a1[ks][1] = (short)f2bf(fa.y);
        a1[ks][2] = (short)f2bf(fa.z); a1[ks][3] = (short)f2bf(fa.w);
        a1[ks][4] = (short)f2bf(fb.x); a1[ks][5] = (short)f2bf(fb.y);
        a1[ks][6] = (short)f2bf(fb.z); a1[ks][7] = (short)f2bf(fb.w);
    }

    f32x4 acc0[9], acc1[9];
#pragma unroll
    for (int c = 0; c < 9; ++c) {
        acc0[c] = (f32x4){0.f, 0.f, 0.f, 0.f};
        acc1[c] = (f32x4){0.f, 0.f, 0.f, 0.f};
    }

    const unsigned short* Brow = &B_lds[l15 * LDSTRIDE + quad * 8];
    const unsigned short* Brow8 = &B_lds[(128 + (l15 & 7)) * LDSTRIDE + quad * 8];
#pragma unroll
    for (int ks = 0; ks < 4; ++ks) {
#pragma unroll
        for (int c = 0; c < 8; ++c) {
            bf16x8 b = *(const bf16x8*)(Brow + (c * 16) * LDSTRIDE + ks * 32);
            acc0[c] = __builtin_amdgcn_mfma_f32_16x16x32_bf16(a0[ks], b, acc0[c], 0, 0, 0);
            acc1[c] = __builtin_amdgcn_mfma_f32_16x16x32_bf16(a1[ks], b, acc1[c], 0, 0, 0);
        }
        bf16x8 b8 = *(const bf16x8*)(Brow8 + ks * 32);
        acc0[8] = __builtin_amdgcn_mfma_f32_16x16x32_bf16(a0[ks], b8, acc0[8], 0, 0, 0);
        acc1[8] = __builtin_amdgcn_mfma_f32_16x16x32_bf16(a1[ks], b8, acc1[8], 0, 0, 0);
    }

    // el/er from acc[8], both tiles: col l15<4 -> el head l15; [4,8) -> er
#pragma unroll
    for (int reg = 0; reg < 4; ++reg) {
        const int ga = nbase + w * 32 + quad * 4 + reg;
        if (ga < N_NODES) {
            if (l15 < 4)      el[ga * 4 + l15] = acc0[8][reg];
            else if (l15 < 8) er[ga * 4 + (l15 - 4)] = acc0[8][reg];
        }
        const int gb = ga + 16;
        if (gb < N_NODES) {
            if (l15 < 4)      el[gb * 4 + l15] = acc1[8][reg];
            else if (l15 < 8) er[gb * 4 + (l15 - 4)] = acc1[8][reg];
        }
    }

    __syncthreads();   // everyone done reading B_lds -> reuse as ft scratch
#pragma unroll
    for (int c = 0; c < 8; ++c) {
#pragma unroll
        for (int reg = 0; reg < 4; ++reg) {
            B_lds[(w * 32 + quad * 4 + reg) * LDSTRIDE + c * 16 + l15] =
                f2h(acc0[c][reg]);                      // FP16 pack, tile 0
            B_lds[(w * 32 + 16 + quad * 4 + reg) * LDSTRIDE + c * 16 + l15] =
                f2h(acc1[c][reg]);                      // FP16 pack, tile 1
        }
    }
    __syncthreads();

    // coalesced repack: 128 rows x 128 cols fp16 -> global int4
#pragma unroll
    for (int i = 0; i < 8; ++i) {
        int idx = t + 256 * i;                // [0,2048)
        int node = idx >> 4, cg = idx & 15;
        int gg = nbase + node;
        if (gg < N_NODES) {
            int4 val = *(const int4*)(&B_lds[node * LDSTRIDE + cg * 8]);
            *(int4*)(&ft[(size_t)gg * 128 + cg * 8]) = val;
        }
    }
}

// ---------------------------------------------------------------------------
// Kernel 2: aggregation — EXACT round-3 floor version (73.4-74.0 us).
// Five structural variants (rounds 0-4) all landed 73.4-79.0 us while VALU
// count varied 2x and per-wave MLP varied 2x; time tracks only FETCH+WRITE
// (~286 MB @ 3.9 TB/s) => at the random-gather fill-path ceiling. The
// round-4 2-node variant cost occupancy (VGPR 36) for no MLP net gain.
// ---------------------------------------------------------------------------
__global__ __launch_bounds__(256) void aggregate_kernel(
    const unsigned short* __restrict__ ft, const float* __restrict__ el,
    const float* __restrict__ er, const int* __restrict__ src,
    const int* __restrict__ seg, float* __restrict__ out)
{
    const int node = blockIdx.x * 4 + (threadIdx.x >> 6);
    if (node >= N_NODES) return;
    const int lane = threadIdx.x & 63;
    const int qt = lane >> 4;         // quarter: edges c0+4qt .. +3
    const int l15 = lane & 15;        // feature group: feats 8*l15..+7
    const int hf = l15 >> 2;          // head of this lane's features/scores

    const int beg = __builtin_amdgcn_readfirstlane(seg[node]);
    const int end = __builtin_amdgcn_readfirstlane(seg[node + 1]);
    const float er_h = er[node * 4 + hf];

    float dpart = 0.f;
    float4 accA = make_float4(0.f, 0.f, 0.f, 0.f);
    float4 accB = make_float4(0.f, 0.f, 0.f, 0.f);

    for (int c0 = beg; c0 < end; c0 += 16) {
        const int cb = c0 + 4 * qt;
        int s4[4];
#pragma unroll
        for (int k = 0; k < 4; ++k) {
            int ci = cb + k;
            s4[k] = src[ci < end ? ci : end - 1];   // clamp (p forced 0)
        }
        float ev[4];
#pragma unroll
        for (int k = 0; k < 4; ++k) ev[k] = el[s4[k] * 4 + hf];
        float p[4];
#pragma unroll
        for (int k = 0; k < 4; ++k) {
            float e = ev[k] + er_h;
            e = (e > 0.f) ? e : NEG_SLOPE * e;
            p[k] = (cb + k < end) ? __expf(e) : 0.f;
            dpart += p[k];
        }
        uint4 v[4];
#pragma unroll
        for (int k = 0; k < 4; ++k)
            v[k] = *(const uint4*)(ft + (((size_t)(unsigned)s4[k]) << 7) + l15 * 8);
#pragma unroll
        for (int k = 0; k < 4; ++k) {
            const float pj = p[k];
            // acc += (float)f16half(v) * pj, one instruction per element
            asm("v_fma_mix_f32 %0, %2, %3, %0 op_sel_hi:[1,0,0]\n\t"
                "v_fma_mix_f32 %1, %2, %3, %1 op_sel:[1,0,0] op_sel_hi:[1,0,0]"
                : "+v"(accA.x), "+v"(accA.y) : "v"(v[k].x), "v"(pj));
            asm("v_fma_mix_f32 %0, %2, %3, %0 op_sel_hi:[1,0,0]\n\t"
                "v_fma_mix_f32 %1, %2, %3, %1 op_sel:[1,0,0] op_sel_hi:[1,0,0]"
                : "+v"(accA.z), "+v"(accA.w) : "v"(v[k].y), "v"(pj));
            asm("v_fma_mix_f32 %0, %2, %3, %0 op_sel_hi:[1,0,0]\n\t"
                "v_fma_mix_f32 %1, %2, %3, %1 op_sel:[1,0,0] op_sel_hi:[1,0,0]"
                : "+v"(accB.x), "+v"(accB.y) : "v"(v[k].z), "v"(pj));
            asm("v_fma_mix_f32 %0, %2, %3, %0 op_sel_hi:[1,0,0]\n\t"
                "v_fma_mix_f32 %1, %2, %3, %1 op_sel:[1,0,0] op_sel_hi:[1,0,0]"
                : "+v"(accB.z), "+v"(accB.w) : "v"(v[k].w), "v"(pj));
        }
    }

    // reduce across quarters (lanes ^16, ^32); dpart rides along
    dpart  += __shfl_xor(dpart, 16);
    accA.x += __shfl_xor(accA.x, 16); accA.y += __shfl_xor(accA.y, 16);
    accA.z += __shfl_xor(accA.z, 16); accA.w += __shfl_xor(accA.w, 16);
    accB.x += __shfl_xor(accB.x, 16); accB.y += __shfl_xor(accB.y, 16);
    accB.z += __shfl_xor(accB.z, 16); accB.w += __shfl_xor(accB.w, 16);
    dpart  += __shfl_xor(dpart, 32);
    accA.x += __shfl_xor(accA.x, 32); accA.y += __shfl_xor(accA.y, 32);
    accA.z += __shfl_xor(accA.z, 32); accA.w += __shfl_xor(accA.w, 32);
    accB.x += __shfl_xor(accB.x, 32); accB.y += __shfl_xor(accB.y, 32);
    accB.z += __shfl_xor(accB.z, 32); accB.w += __shfl_xor(accB.w, 32);

    const float inv = (dpart > 0.f) ? 1.f / dpart : 0.f; // degree-0 -> zeros

    if (qt == 0) {
        float4 o0 = make_float4(accA.x * inv, accA.y * inv, accA.z * inv, accA.w * inv);
        float4 o1 = make_float4(accB.x * inv, accB.y * inv, accB.z * inv, accB.w * inv);
        float* op = out + (size_t)node * 128 + l15 * 8;
        *(float4*)op = o0;
        *(float4*)(op + 4) = o1;
    }
}

// ---------------------------------------------------------------------------
extern "C" void kernel_launch(void* const* d_in, const int* in_sizes, int n_in,
                              void* d_out, int out_size, void* d_ws, size_t ws_size,
                              hipStream_t stream) {
    const float* feat   = (const float*)d_in[0];
    const int*   src    = (const int*)d_in[1];
    const int*   dst    = (const int*)d_in[2];
    const float* W      = (const float*)d_in[3];
    const float* attn_l = (const float*)d_in[4];
    const float* attn_r = (const float*)d_in[5];
    float* out = (float*)d_out;

    unsigned short* ft = (unsigned short*)d_ws;               // 12.8M fp16
    float* el  = (float*)(ft + (size_t)12800000);
    float* er  = el + 400000;
    unsigned short* Wt2 = (unsigned short*)(er + 400000);     // 136*128 bf16
    int* seg = (int*)(Wt2 + 136 * 128);                       // 100001 int

    prep_seg_kernel<<<SEG_BLOCKS + 68, 256, 0, stream>>>(
        dst, seg, W, attn_l, attn_r, Wt2);
    gemm_kernel<<<(N_NODES + 127) / 128, 256, 0, stream>>>(feat, Wt2, ft, el, er);
    aggregate_kernel<<<(N_NODES + 3) / 4, 256, 0, stream>>>(
        ft, el, er, src, seg, out);
}

// Round 8
// 191.235 us; speedup vs baseline: 1.0109x; 1.0063x over previous
//
#include <hip/hip_runtime.h>

#define N_NODES 100000
#define N_EDGES 1600000
#define NUM_HEADS 4
#define NEG_SLOPE 0.2f
#define LDSTRIDE 136   // 16-bit elems: 272 B rows (68 dwords ≡ 4 mod 32 banks)
#define GEMM_BLOCKS 782   // ceil(100000/128)
#define SEG_BLOCKS 1563   // ceil(400000/256) threads, 4 edges each

typedef __attribute__((ext_vector_type(8))) short bf16x8;
typedef __attribute__((ext_vector_type(4))) float f32x4;

__device__ __forceinline__ unsigned short f2bf(float x) {
    union { float f; unsigned u; } v; v.f = x;
    unsigned r = v.u + 0x7fffu + ((v.u >> 16) & 1u);   // RN-even
    return (unsigned short)(r >> 16);
}
__device__ __forceinline__ unsigned short f2h(float x) {
    union { _Float16 h; unsigned short u; } v; v.h = (_Float16)x;  // v_cvt_f16_f32 RNE
    return v.u;
}

// ---------------------------------------------------------------------------
// Kernel 0: Wt2 prep only (68 blocks — seg moved into the gemm dispatch).
//   rows 0..127  : Wt2[n][k] = bf16(W[k][n])
//   rows 128..131: bf16(wl[k][h]);  132..135: bf16(wr[k][h])
// ---------------------------------------------------------------------------
__global__ __launch_bounds__(256) void prep_kernel(
    const float* __restrict__ W, const float* __restrict__ attn_l,
    const float* __restrict__ attn_r, unsigned short* __restrict__ Wt2)
{
    int idx = blockIdx.x * 256 + threadIdx.x;   // [0, 17408)
    if (idx >= 136 * 128) return;
    int n = idx >> 7, k = idx & 127;
    if (n < 128) {
        Wt2[idx] = f2bf(W[k * 128 + n]);
    } else {
        int h = (n - 128) & 3;
        const float* av = ((n - 128) < 4 ? attn_l : attn_r) + h * 32;
        const float* col = W + k * 128 + h * 32;
        float s = 0.f;
#pragma unroll
        for (int d2 = 0; d2 < 32; ++d2) s += col[d2] * av[d2];
        Wt2[idx] = f2bf(s);
    }
}

// ---------------------------------------------------------------------------
// Kernel 1: gemm + seg FUSED into one dispatch. The seg scan (from sorted
// dst) has no dependency on the GEMM; appending its 1563 blocks to the gemm
// grid lets it fill the gemm's latency slack instead of serializing as a
// separate kernel (removes its standalone pass + one kernel-boundary drain).
// Blocks [0, GEMM_BLOCKS): round-6 gemm v3 (128 nodes/block, 2:1
// MFMA:ds_read, feat prefetch before LDS staging, fp16 ft).
// Blocks [GEMM_BLOCKS, +SEG_BLOCKS): seg[] from sorted dst, 4 edges/thread.
// ---------------------------------------------------------------------------
__global__ __launch_bounds__(256, 3) void gemm_seg_kernel(
    const float* __restrict__ feat, const unsigned short* __restrict__ Wt2,
    unsigned short* __restrict__ ft, float* __restrict__ el,
    float* __restrict__ er, const int* __restrict__ dst,
    int* __restrict__ seg)
{
    __shared__ __align__(16) unsigned short B_lds[136 * LDSTRIDE];  // 36992 B

    if (blockIdx.x >= GEMM_BLOCKS) {
        // ---- seg part (block-uniform branch; no barriers on this path) ----
        int i4 = (int)(blockIdx.x - GEMM_BLOCKS) * 256 + threadIdx.x;
        if (i4 >= N_EDGES / 4) return;
        const int e0 = 4 * i4;
        const int4 d = ((const int4*)dst)[i4];
        const int dp = (e0 == 0) ? -1 : dst[e0 - 1];
        for (int n = dp + 1; n <= d.x; ++n) seg[n] = e0;
        for (int n = d.x + 1; n <= d.y; ++n) seg[n] = e0 + 1;
        for (int n = d.y + 1; n <= d.z; ++n) seg[n] = e0 + 2;
        for (int n = d.z + 1; n <= d.w; ++n) seg[n] = e0 + 3;
        if (e0 + 4 == N_EDGES)
            for (int n = d.w + 1; n <= N_NODES; ++n) seg[n] = N_EDGES;
        return;
    }

    // ---- gemm part (exact round-6 v3 body) ----
    const int t = threadIdx.x;
    const int nbase = blockIdx.x * 128;
    const int w = t >> 6, lane = t & 63;
    const int l15 = lane & 15, quad = lane >> 4;

    int g0 = nbase + w * 32 + l15;      if (g0 >= N_NODES) g0 = N_NODES - 1;
    int g1 = nbase + w * 32 + 16 + l15; if (g1 >= N_NODES) g1 = N_NODES - 1;
    const float4* f40 = (const float4*)feat + (size_t)g0 * 32 + quad * 2;
    const float4* f41 = (const float4*)feat + (size_t)g1 * 32 + quad * 2;
    float4 fr0[8], fr1[8];
#pragma unroll
    for (int ks = 0; ks < 4; ++ks) {
        fr0[2 * ks] = f40[ks * 8]; fr0[2 * ks + 1] = f40[ks * 8 + 1];
        fr1[2 * ks] = f41[ks * 8]; fr1[2 * ks + 1] = f41[ks * 8 + 1];
    }

    {   // stage Wt2 (136 rows x 128 k bf16) -> B_lds, coalesced 16B
        const int4* Wt4 = (const int4*)Wt2;
#pragma unroll
        for (int i = 0; i < 9; ++i) {
            int idx = t + 256 * i;            // [0,2304) guard to 2176
            if (idx < 2176) {
                int n = idx >> 4, cg = idx & 15;
                *(int4*)(&B_lds[n * LDSTRIDE + cg * 8]) = Wt4[idx];
            }
        }
    }
    __syncthreads();

    bf16x8 a0[4], a1[4];
#pragma unroll
    for (int ks = 0; ks < 4; ++ks) {
        float4 fa = fr0[2 * ks], fb = fr0[2 * ks + 1];
        a0[ks][0] = (short)f2bf(fa.x); a0[ks][1] = (short)f2bf(fa.y);
        a0[ks][2] = (short)f2bf(fa.z); a0[ks][3] = (short)f2bf(fa.w);
        a0[ks][4] = (short)f2bf(fb.x); a0[ks][5] = (short)f2bf(fb.y);
        a0[ks][6] = (short)f2bf(fb.z); a0[ks][7] = (short)f2bf(fb.w);
        fa = fr1[2 * ks]; fb = fr1[2 * ks + 1];
        a1[ks][0] = (short)f2bf(fa.x); a1[ks][1] = (short)f2bf(fa.y);
        a1[ks][2] = (short)f2bf(fa.z); a1[ks][3] = (short)f2bf(fa.w);
        a1[ks][4] = (short)f2bf(fb.x); a1[ks][5] = (short)f2bf(fb.y);
        a1[ks][6] = (short)f2bf(fb.z); a1[ks][7] = (short)f2bf(fb.w);
    }

    f32x4 acc0[9], acc1[9];
#pragma unroll
    for (int c = 0; c < 9; ++c) {
        acc0[c] = (f32x4){0.f, 0.f, 0.f, 0.f};
        acc1[c] = (f32x4){0.f, 0.f, 0.f, 0.f};
    }

    const unsigned short* Brow = &B_lds[l15 * LDSTRIDE + quad * 8];
    const unsigned short* Brow8 = &B_lds[(128 + (l15 & 7)) * LDSTRIDE + quad * 8];
#pragma unroll
    for (int ks = 0; ks < 4; ++ks) {
#pragma unroll
        for (int c = 0; c < 8; ++c) {
            bf16x8 b = *(const bf16x8*)(Brow + (c * 16) * LDSTRIDE + ks * 32);
            acc0[c] = __builtin_amdgcn_mfma_f32_16x16x32_bf16(a0[ks], b, acc0[c], 0, 0, 0);
            acc1[c] = __builtin_amdgcn_mfma_f32_16x16x32_bf16(a1[ks], b, acc1[c], 0, 0, 0);
        }
        bf16x8 b8 = *(const bf16x8*)(Brow8 + ks * 32);
        acc0[8] = __builtin_amdgcn_mfma_f32_16x16x32_bf16(a0[ks], b8, acc0[8], 0, 0, 0);
        acc1[8] = __builtin_amdgcn_mfma_f32_16x16x32_bf16(a1[ks], b8, acc1[8], 0, 0, 0);
    }

    // el/er from acc[8], both tiles: col l15<4 -> el head l15; [4,8) -> er
#pragma unroll
    for (int reg = 0; reg < 4; ++reg) {
        const int ga = nbase + w * 32 + quad * 4 + reg;
        if (ga < N_NODES) {
            if (l15 < 4)      el[ga * 4 + l15] = acc0[8][reg];
            else if (l15 < 8) er[ga * 4 + (l15 - 4)] = acc0[8][reg];
        }
        const int gb = ga + 16;
        if (gb < N_NODES) {
            if (l15 < 4)      el[gb * 4 + l15] = acc1[8][reg];
            else if (l15 < 8) er[gb * 4 + (l15 - 4)] = acc1[8][reg];
        }
    }

    __syncthreads();   // everyone done reading B_lds -> reuse as ft scratch
#pragma unroll
    for (int c = 0; c < 8; ++c) {
#pragma unroll
        for (int reg = 0; reg < 4; ++reg) {
            B_lds[(w * 32 + quad * 4 + reg) * LDSTRIDE + c * 16 + l15] =
                f2h(acc0[c][reg]);                      // FP16 pack, tile 0
            B_lds[(w * 32 + 16 + quad * 4 + reg) * LDSTRIDE + c * 16 + l15] =
                f2h(acc1[c][reg]);                      // FP16 pack, tile 1
        }
    }
    __syncthreads();

    // coalesced repack: 128 rows x 128 cols fp16 -> global int4
#pragma unroll
    for (int i = 0; i < 8; ++i) {
        int idx = t + 256 * i;                // [0,2048)
        int node = idx >> 4, cg = idx & 15;
        int gg = nbase + node;
        if (gg < N_NODES) {
            int4 val = *(const int4*)(&B_lds[node * LDSTRIDE + cg * 8]);
            *(int4*)(&ft[(size_t)gg * 128 + cg * 8]) = val;
        }
    }
}

// ---------------------------------------------------------------------------
// Kernel 2: aggregation — round-6 floor core (73.4-74.5 us; at the random-
// gather fill ceiling: 286 MB @ ~3.9 TB/s, six structural variants within
// noise). ONE change: `out` stores are NONTEMPORAL (via clang ext_vector
// f32x4 — __builtin_nontemporal_store rejects HIP_vector_type). out (50 MB,
// write-only, never re-read) was flowing through L2 and evicting ft lines
// during the kernel; NT stores reduce that eviction -> higher ft L2 hit
// rate -> lower FETCH_SIZE, a direct attack on the binding fill path.
// ---------------------------------------------------------------------------
__global__ __launch_bounds__(256) void aggregate_kernel(
    const unsigned short* __restrict__ ft, const float* __restrict__ el,
    const float* __restrict__ er, const int* __restrict__ src,
    const int* __restrict__ seg, float* __restrict__ out)
{
    const int node = blockIdx.x * 4 + (threadIdx.x >> 6);
    if (node >= N_NODES) return;
    const int lane = threadIdx.x & 63;
    const int qt = lane >> 4;         // quarter: edges c0+4qt .. +3
    const int l15 = lane & 15;        // feature group: feats 8*l15..+7
    const int hf = l15 >> 2;          // head of this lane's features/scores

    const int beg = __builtin_amdgcn_readfirstlane(seg[node]);
    const int end = __builtin_amdgcn_readfirstlane(seg[node + 1]);
    const float er_h = er[node * 4 + hf];

    float dpart = 0.f;
    float4 accA = make_float4(0.f, 0.f, 0.f, 0.f);
    float4 accB = make_float4(0.f, 0.f, 0.f, 0.f);

    for (int c0 = beg; c0 < end; c0 += 16) {
        const int cb = c0 + 4 * qt;
        int s4[4];
#pragma unroll
        for (int k = 0; k < 4; ++k) {
            int ci = cb + k;
            s4[k] = src[ci < end ? ci : end - 1];   // clamp (p forced 0)
        }
        float ev[4];
#pragma unroll
        for (int k = 0; k < 4; ++k) ev[k] = el[s4[k] * 4 + hf];
        float p[4];
#pragma unroll
        for (int k = 0; k < 4; ++k) {
            float e = ev[k] + er_h;
            e = (e > 0.f) ? e : NEG_SLOPE * e;
            p[k] = (cb + k < end) ? __expf(e) : 0.f;
            dpart += p[k];
        }
        uint4 v[4];
#pragma unroll
        for (int k = 0; k < 4; ++k)
            v[k] = *(const uint4*)(ft + (((size_t)(unsigned)s4[k]) << 7) + l15 * 8);
#pragma unroll
        for (int k = 0; k < 4; ++k) {
            const float pj = p[k];
            // acc += (float)f16half(v) * pj, one instruction per element
            asm("v_fma_mix_f32 %0, %2, %3, %0 op_sel_hi:[1,0,0]\n\t"
                "v_fma_mix_f32 %1, %2, %3, %1 op_sel:[1,0,0] op_sel_hi:[1,0,0]"
                : "+v"(accA.x), "+v"(accA.y) : "v"(v[k].x), "v"(pj));
            asm("v_fma_mix_f32 %0, %2, %3, %0 op_sel_hi:[1,0,0]\n\t"
                "v_fma_mix_f32 %1, %2, %3, %1 op_sel:[1,0,0] op_sel_hi:[1,0,0]"
                : "+v"(accA.z), "+v"(accA.w) : "v"(v[k].y), "v"(pj));
            asm("v_fma_mix_f32 %0, %2, %3, %0 op_sel_hi:[1,0,0]\n\t"
                "v_fma_mix_f32 %1, %2, %3, %1 op_sel:[1,0,0] op_sel_hi:[1,0,0]"
                : "+v"(accB.x), "+v"(accB.y) : "v"(v[k].z), "v"(pj));
            asm("v_fma_mix_f32 %0, %2, %3, %0 op_sel_hi:[1,0,0]\n\t"
                "v_fma_mix_f32 %1, %2, %3, %1 op_sel:[1,0,0] op_sel_hi:[1,0,0]"
                : "+v"(accB.z), "+v"(accB.w) : "v"(v[k].w), "v"(pj));
        }
    }

    // reduce across quarters (lanes ^16, ^32); dpart rides along
    dpart  += __shfl_xor(dpart, 16);
    accA.x += __shfl_xor(accA.x, 16); accA.y += __shfl_xor(accA.y, 16);
    accA.z += __shfl_xor(accA.z, 16); accA.w += __shfl_xor(accA.w, 16);
    accB.x += __shfl_xor(accB.x, 16); accB.y += __shfl_xor(accB.y, 16);
    accB.z += __shfl_xor(accB.z, 16); accB.w += __shfl_xor(accB.w, 16);
    dpart  += __shfl_xor(dpart, 32);
    accA.x += __shfl_xor(accA.x, 32); accA.y += __shfl_xor(accA.y, 32);
    accA.z += __shfl_xor(accA.z, 32); accA.w += __shfl_xor(accA.w, 32);
    accB.x += __shfl_xor(accB.x, 32); accB.y += __shfl_xor(accB.y, 32);
    accB.z += __shfl_xor(accB.z, 32); accB.w += __shfl_xor(accB.w, 32);

    const float inv = (dpart > 0.f) ? 1.f / dpart : 0.f; // degree-0 -> zeros

    if (qt == 0) {
        f32x4 o0 = {accA.x * inv, accA.y * inv, accA.z * inv, accA.w * inv};
        f32x4 o1 = {accB.x * inv, accB.y * inv, accB.z * inv, accB.w * inv};
        float* op = out + (size_t)node * 128 + l15 * 8;
        __builtin_nontemporal_store(o0, (f32x4*)op);         // write-only out:
        __builtin_nontemporal_store(o1, (f32x4*)(op + 4));   // don't evict ft
    }
}

// ---------------------------------------------------------------------------
extern "C" void kernel_launch(void* const* d_in, const int* in_sizes, int n_in,
                              void* d_out, int out_size, void* d_ws, size_t ws_size,
                              hipStream_t stream) {
    const float* feat   = (const float*)d_in[0];
    const int*   src    = (const int*)d_in[1];
    const int*   dst    = (const int*)d_in[2];
    const float* W      = (const float*)d_in[3];
    const float* attn_l = (const float*)d_in[4];
    const float* attn_r = (const float*)d_in[5];
    float* out = (float*)d_out;

    unsigned short* ft = (unsigned short*)d_ws;               // 12.8M fp16
    float* el  = (float*)(ft + (size_t)12800000);
    float* er  = el + 400000;
    unsigned short* Wt2 = (unsigned short*)(er + 400000);     // 136*128 bf16
    int* seg = (int*)(Wt2 + 136 * 128);                       // 100001 int

    prep_kernel<<<68, 256, 0, stream>>>(W, attn_l, attn_r, Wt2);
    gemm_seg_kernel<<<GEMM_BLOCKS + SEG_BLOCKS, 256, 0, stream>>>(
        feat, Wt2, ft, el, er, dst, seg);
    aggregate_kernel<<<(N_NODES + 3) / 4, 256, 0, stream>>>(
        ft, el, er, src, seg, out);
}